// Round 1
// baseline (379.736 us; speedup 1.0000x reference)
//
#include <hip/hip_runtime.h>

typedef __bf16 bf16;
typedef __bf16 bf16x8 __attribute__((ext_vector_type(8)));
typedef __bf16 bf16x4 __attribute__((ext_vector_type(4)));
typedef float f32x4 __attribute__((ext_vector_type(4)));

#define N_TOK 9216
#define SRC 1024
#define EDIM 256
#define NE 16384
#define GROUPS 16
#define GSIZE 1024  // codes per argmin group
#define LOSS_DENOM 2359296.0f  // 16*576*256

__device__ __forceinline__ void async_load16(const void* g, void* l) {
  __builtin_amdgcn_global_load_lds(
      (__attribute__((address_space(1))) void*)(void*)(const_cast<void*>(g)),
      (__attribute__((address_space(3))) void*)l, 16, 0, 0);
}

__device__ __forceinline__ f32x4 mfma16(bf16x8 a, bf16x8 b, f32x4 c) {
  return __builtin_amdgcn_mfma_f32_16x16x32_bf16(a, b, c, 0, 0, 0);
}

// ---------------- prep kernels ----------------

// cast x (9,437,184 f32) -> bf16; thread handles 4 elems. Also zeros loss acc.
__global__ __launch_bounds__(256) void k_cast_x(const float* __restrict__ x,
                                                bf16* __restrict__ xb,
                                                float* __restrict__ lacc) {
  int i = blockIdx.x * 256 + threadIdx.x;
  float4 v = ((const float4*)x)[i];
  bf16x4 o = {(bf16)v.x, (bf16)v.y, (bf16)v.z, (bf16)v.w};
  *(bf16x4*)(xb + 4 * i) = o;
  if (i == 0) *lacc = 0.f;
}

// transpose+cast enc_w [1024,256]->enc_wT[256,1024], dec_w [256,1024]->dec_wT[1024,256]
__global__ __launch_bounds__(256) void k_prep_w(const float* __restrict__ enc_w,
                                                const float* __restrict__ dec_w,
                                                bf16* __restrict__ enc_wT,
                                                bf16* __restrict__ dec_wT) {
  int id = blockIdx.x * 256 + threadIdx.x;  // 262144 threads
  {
    int n = id >> 10, k = id & 1023;
    enc_wT[id] = (bf16)enc_w[k * EDIM + n];
  }
  {
    int n = id >> 8, k = id & 255;
    dec_wT[id] = (bf16)dec_w[k * SRC + n];
  }
}

// codebook: cast to bf16 + row squared norms. One wave per row (4 rows/block).
__global__ __launch_bounds__(256) void k_prep_cb(const float* __restrict__ cb,
                                                 bf16* __restrict__ cbb,
                                                 float* __restrict__ e2) {
  int row = blockIdx.x * 4 + (threadIdx.x >> 6);
  int lane = threadIdx.x & 63;
  float4 v = ((const float4*)(cb + (size_t)row * EDIM))[lane];
  bf16x4 o = {(bf16)v.x, (bf16)v.y, (bf16)v.z, (bf16)v.w};
  *(bf16x4*)(cbb + (size_t)row * EDIM + lane * 4) = o;
  float s = v.x * v.x + v.y * v.y + v.z * v.z + v.w * v.w;
#pragma unroll
  for (int off = 32; off; off >>= 1) s += __shfl_xor(s, off, 64);
  if (lane == 0) e2[row] = s;
}

// ---------------- generic bf16 MFMA GEMM ----------------
// C[M,N] = A[M,K] * BT[N,K]^T + bias[N]. 64x64 block tile, BK=32, 4 waves (2x2 of 32x32).
__global__ __launch_bounds__(256) void k_gemm(const bf16* __restrict__ A,
                                              const bf16* __restrict__ BT,
                                              const float* __restrict__ bias,
                                              float* __restrict__ Cf,
                                              bf16* __restrict__ Cb, int K, int N) {
  __shared__ __align__(16) bf16 As[64 * 32];
  __shared__ __align__(16) bf16 Bs[64 * 32];
  const int tid = threadIdx.x;
  const int wid = tid >> 6, lane = tid & 63;
  const int col = lane & 15, quad = lane >> 4;
  const int wm = (wid >> 1) * 32, wn = (wid & 1) * 32;
  const int bm = blockIdx.x * 64, bn = blockIdx.y * 64;
  // staging: slot = tid, each slot = 16B; row = slot/4, k8 = (slot%4)*8
  const int arow = tid >> 2, ak8 = (tid & 3) * 8;
  const bf16* Ag = A + (size_t)(bm + arow) * K + ak8;
  const bf16* Bg = BT + (size_t)(bn + arow) * K + ak8;
  char* AsW = (char*)As + wid * 1024;  // wave-uniform LDS base; lane*16 appended by HW
  char* BsW = (char*)Bs + wid * 1024;
  f32x4 acc[2][2] = {};
  for (int kc = 0; kc < K; kc += 32) {
    async_load16(Ag + kc, AsW);
    async_load16(Bg + kc, BsW);
    __syncthreads();
    bf16x8 af[2], bfr[2];
#pragma unroll
    for (int t = 0; t < 2; t++)
      af[t] = *(const bf16x8*)&As[(wm + t * 16 + col) * 32 + quad * 8];
#pragma unroll
    for (int u = 0; u < 2; u++)
      bfr[u] = *(const bf16x8*)&Bs[(wn + u * 16 + col) * 32 + quad * 8];
#pragma unroll
    for (int t = 0; t < 2; t++)
#pragma unroll
      for (int u = 0; u < 2; u++) acc[t][u] = mfma16(af[t], bfr[u], acc[t][u]);
    __syncthreads();
  }
#pragma unroll
  for (int t = 0; t < 2; t++) {
#pragma unroll
    for (int u = 0; u < 2; u++) {
      int n = bn + wn + u * 16 + col;
      float bv = bias[n];
#pragma unroll
      for (int r = 0; r < 4; r++) {
        int m = bm + wm + t * 16 + quad * 4 + r;
        float v = acc[t][u][r] + bv;
        Cf[(size_t)m * N + n] = v;
        if (Cb) Cb[(size_t)m * N + n] = (bf16)v;
      }
    }
  }
}

// ---------------- fused cross-GEMM + argmin ----------------
// Block: 128 tokens x one group of 1024 codes. 4 waves, each 32 tokens.
// z fragments register-resident; codebook tiles (16 codes x 256 k) staged in LDS
// with XOR swizzle (16B-slot (row,k16) stored at row*32 + (k16^row)) to spread banks.
__global__ __launch_bounds__(256) void k_argmin(const bf16* __restrict__ zb,
                                                const bf16* __restrict__ cbb,
                                                const float* __restrict__ e2,
                                                float* __restrict__ pval,
                                                int* __restrict__ pidx) {
  __shared__ __align__(16) bf16 Cs[16 * 256];
  const int tid = threadIdx.x;
  const int wid = tid >> 6, lane = tid & 63;
  const int col = lane & 15, quad = lane >> 4;
  const int tb = blockIdx.x * 128 + wid * 32;
  const int g = blockIdx.y;
  // A fragments: 2 m-tiles x 8 k-steps (K=256)
  bf16x8 af[2][8];
#pragma unroll
  for (int t = 0; t < 2; t++)
#pragma unroll
    for (int s = 0; s < 8; s++)
      af[t][s] = *(const bf16x8*)&zb[(size_t)(tb + t * 16 + col) * EDIM + s * 32 + quad * 8];
  float bestv[2][4];
  int besti[2][4];
#pragma unroll
  for (int t = 0; t < 2; t++)
#pragma unroll
    for (int r = 0; r < 4; r++) { bestv[t][r] = 3.4e38f; besti[t][r] = 0; }
  // staging: 512 slots of 16B; this thread's two slots
  const int s0 = wid * 128 + lane, s1 = s0 + 64;
  const int r0 = s0 >> 5, k0 = (s0 & 31) ^ r0;
  const int r1 = s1 >> 5, k1 = (s1 & 31) ^ r1;
  char* base0 = (char*)Cs + wid * 2048;
  char* base1 = base0 + 1024;
  for (int tile = 0; tile < GSIZE / 16; ++tile) {
    const int cb0 = g * GSIZE + tile * 16;
    async_load16(cbb + (size_t)(cb0 + r0) * EDIM + k0 * 8, base0);
    async_load16(cbb + (size_t)(cb0 + r1) * EDIM + k1 * 8, base1);
    __syncthreads();
    f32x4 c0 = {}, c1 = {};
#pragma unroll
    for (int s = 0; s < 8; s++) {
      int k16 = s * 4 + quad;
      bf16x8 bfrag = *(const bf16x8*)((const char*)Cs + (col * 32 + (k16 ^ col)) * 16);
      c0 = mfma16(af[0][s], bfrag, c0);
      c1 = mfma16(af[1][s], bfrag, c1);
    }
    float ev = e2[cb0 + col];
    int code = cb0 + col;
#pragma unroll
    for (int r = 0; r < 4; r++) {
      float d0 = ev - 2.f * c0[r];
      if (d0 < bestv[0][r]) { bestv[0][r] = d0; besti[0][r] = code; }
      float d1 = ev - 2.f * c1[r];
      if (d1 < bestv[1][r]) { bestv[1][r] = d1; besti[1][r] = code; }
    }
    __syncthreads();
  }
  // reduce across the 16 columns (lanes sharing quad)
#pragma unroll
  for (int off = 1; off < 16; off <<= 1) {
#pragma unroll
    for (int t = 0; t < 2; t++)
#pragma unroll
      for (int r = 0; r < 4; r++) {
        float ov = __shfl_xor(bestv[t][r], off, 64);
        int oi = __shfl_xor(besti[t][r], off, 64);
        if (ov < bestv[t][r] || (ov == bestv[t][r] && oi < besti[t][r])) {
          bestv[t][r] = ov;
          besti[t][r] = oi;
        }
      }
  }
  if (col == 0) {
#pragma unroll
    for (int t = 0; t < 2; t++)
#pragma unroll
      for (int r = 0; r < 4; r++) {
        int token = tb + t * 16 + quad * 4 + r;
        pval[token * GROUPS + g] = bestv[t][r];
        pidx[token * GROUPS + g] = besti[t][r];
      }
  }
}

// ---------------- gather + loss partial ----------------
// One wave per token: combine 16 group candidates, gather z_q (fp32->bf16), loss sum.
__global__ __launch_bounds__(256) void k_gather(const float* __restrict__ cb,
                                                const float* __restrict__ zf,
                                                const float* __restrict__ pval,
                                                const int* __restrict__ pidx,
                                                bf16* __restrict__ zqb,
                                                float* __restrict__ lacc) {
  int token = blockIdx.x * 4 + (threadIdx.x >> 6);
  int lane = threadIdx.x & 63;
  float v = 3.4e38f;
  int idx = 0;
  if (lane < 16) {
    v = pval[token * GROUPS + lane];
    idx = pidx[token * GROUPS + lane];
  }
#pragma unroll
  for (int off = 1; off < 16; off <<= 1) {
    float ov = __shfl_xor(v, off, 64);
    int oi = __shfl_xor(idx, off, 64);
    if (ov < v || (ov == v && oi < idx)) { v = ov; idx = oi; }
  }
  idx = __shfl(idx, 0, 64);
  float4 q = ((const float4*)(cb + (size_t)idx * EDIM))[lane];
  float4 z = ((const float4*)(zf + (size_t)token * EDIM))[lane];
  bf16x4 o = {(bf16)q.x, (bf16)q.y, (bf16)q.z, (bf16)q.w};
  *(bf16x4*)(zqb + (size_t)token * EDIM + lane * 4) = o;
  float dx = q.x - z.x, dy = q.y - z.y, dz = q.z - z.z, dw = q.w - z.w;
  float s = dx * dx + dy * dy + dz * dz + dw * dw;
#pragma unroll
  for (int off = 32; off; off >>= 1) s += __shfl_xor(s, off, 64);
  if (lane == 0) atomicAdd(lacc, s);
}

__global__ void k_loss(const float* __restrict__ lacc, float* __restrict__ outl) {
  *outl = 1.25f * (*lacc) / LOSS_DENOM;
}

// ---------------- launch ----------------
extern "C" void kernel_launch(void* const* d_in, const int* in_sizes, int n_in,
                              void* d_out, int out_size, void* d_ws, size_t ws_size,
                              hipStream_t stream) {
  const float* x = (const float*)d_in[0];
  const float* enc_w = (const float*)d_in[1];
  const float* enc_b = (const float*)d_in[2];
  const float* cb = (const float*)d_in[3];
  const float* dec_w = (const float*)d_in[4];
  const float* dec_b = (const float*)d_in[5];
  float* out = (float*)d_out;
  float* out_loss = out + (size_t)N_TOK * SRC;

  char* ws = (char*)d_ws;
  bf16* xb = (bf16*)(ws + 0);              // 18,874,368 B
  bf16* enc_wT = (bf16*)(ws + 18874368);   //    524,288 B
  bf16* dec_wT = (bf16*)(ws + 19398656);   //    524,288 B
  float* zf = (float*)(ws + 19922944);     //  9,437,184 B
  bf16* zb = (bf16*)(ws + 29360128);       //  4,718,592 B
  bf16* cbb = (bf16*)(ws + 34078720);      //  8,388,608 B
  float* e2 = (float*)(ws + 42467328);     //     65,536 B
  float* pval = (float*)(ws + 42532864);   //    589,824 B
  int* pidx = (int*)(ws + 43122688);       //    589,824 B
  bf16* zqb = (bf16*)(ws + 43712512);      //  4,718,592 B
  float* lacc = (float*)(ws + 48431104);   //          4 B  (~46.2 MiB total)

  k_cast_x<<<9216, 256, 0, stream>>>(x, xb, lacc);
  k_prep_w<<<1024, 256, 0, stream>>>(enc_w, dec_w, enc_wT, dec_wT);
  k_prep_cb<<<4096, 256, 0, stream>>>(cb, cbb, e2);
  // encoder: z = x @ enc_w + enc_b  (M=9216, K=1024, N=256), dual f32+bf16 output
  k_gemm<<<dim3(144, 4), 256, 0, stream>>>(xb, enc_wT, enc_b, zf, zb, 1024, 256);
  // fused distance + argmin over 16 code groups
  k_argmin<<<dim3(72, GROUPS), 256, 0, stream>>>(zb, cbb, e2, pval, pidx);
  // final argmin across groups, gather z_q, loss partials
  k_gather<<<2304, 256, 0, stream>>>(cb, zf, pval, pidx, zqb, lacc);
  // decoder: out = z_q @ dec_w + dec_b  (M=9216, K=256, N=1024)
  k_gemm<<<dim3(144, 16), 256, 0, stream>>>(zqb, dec_wT, dec_b, out, nullptr, 256, 1024);
  k_loss<<<1, 1, 0, stream>>>(lacc, out_loss);
}